// Round 5
// baseline (684.831 us; speedup 1.0000x reference)
//
#include <hip/hip_runtime.h>
#include <hip/hip_bf16.h>

#define NNODES 100000
#define NEDGES 1600000
#define NEG_SLOPE 0.2f
#define SCAN_BLOCKS ((NNODES + 255) / 256)   // 391 = also bucket count (256 nodes/bucket)
#define NB SCAN_BLOCKS
#define BCAP 1000                            // per-(replica,bucket) capacity; mean fill 512

__device__ __forceinline__ float wave_sum64(float v) {
#pragma unroll
    for (int off = 1; off < 64; off <<= 1) v += __shfl_xor(v, off, 64);
    return v;
}

__device__ __forceinline__ int wave_sum64i(int v) {
#pragma unroll
    for (int off = 1; off < 64; off <<= 1) v += __shfl_xor(v, off, 64);
    return v;
}

// ---------------- CSR build ----------------

__global__ __launch_bounds__(256) void k_hist(const int* __restrict__ dst,
                                              const float* __restrict__ ea,
                                              int* __restrict__ cnt,
                                              float* __restrict__ easum) {
    int wave = threadIdx.x >> 6, lane = threadIdx.x & 63;
    float s = 0.f;
    for (int i = blockIdx.x * 256 + threadIdx.x; i < NEDGES; i += gridDim.x * 256) {
        atomicAdd(&cnt[dst[i]], 1);
        s += ea[i];
    }
    s = wave_sum64(s);
    __shared__ float ws[4];
    if (lane == 0) ws[wave] = s;
    __syncthreads();
    if (threadIdx.x == 0) atomicAdd(easum, ws[0] + ws[1] + ws[2] + ws[3]);
}

// ---- device-wide exclusive scan of cnt[NNODES] -> rowptr ----

__global__ __launch_bounds__(256) void k_partial(const int* __restrict__ cnt,
                                                 int* __restrict__ bsum) {
    int i = blockIdx.x * 256 + threadIdx.x;
    int lane = threadIdx.x & 63, wave = threadIdx.x >> 6;
    int v = (i < NNODES) ? cnt[i] : 0;
    v = wave_sum64i(v);
    __shared__ int ws[4];
    if (lane == 0) ws[wave] = v;
    __syncthreads();
    if (threadIdx.x == 0) bsum[blockIdx.x] = ws[0] + ws[1] + ws[2] + ws[3];
}

__global__ __launch_bounds__(512) void k_scanb(const int* __restrict__ bsum,
                                               int* __restrict__ boff,
                                               int* __restrict__ rowptr) {
    __shared__ int sh[512];
    int t = threadIdx.x;
    int v = (t < SCAN_BLOCKS) ? bsum[t] : 0;
    sh[t] = v;
    __syncthreads();
    for (int off = 1; off < 512; off <<= 1) {
        int u = (t >= off) ? sh[t - off] : 0;
        __syncthreads();
        sh[t] += u;
        __syncthreads();
    }
    if (t < SCAN_BLOCKS) boff[t] = sh[t] - v;
    if (t == SCAN_BLOCKS - 1) rowptr[NNODES] = sh[t];
}

__global__ __launch_bounds__(256) void k_scanfin(const int* __restrict__ cnt,
                                                 const int* __restrict__ boff,
                                                 int* __restrict__ rowptr) {
    int t = threadIdx.x, lane = t & 63, wave = t >> 6;
    int i = blockIdx.x * 256 + t;
    int x = (i < NNODES) ? cnt[i] : 0;
    int orig = x;
#pragma unroll
    for (int off = 1; off < 64; off <<= 1) {
        int u = __shfl_up(x, off, 64);
        if (lane >= off) x += u;
    }
    __shared__ int ws[4];
    if (lane == 63) ws[wave] = x;
    __syncthreads();
    int wexc = 0;
    for (int w = 0; w < wave; ++w) wexc += ws[w];
    if (i < NNODES) rowptr[i] = boff[blockIdx.x] + wexc + x - orig;
}

// ---- XCD-local two-phase scatter ----
// Phase A: scatter edges to (replica=blockIdx&7, bucket=dst>>8) regions.
// Round-robin block->XCD dispatch makes each replica region ~XCD-private, so
// dirty lines live in one L2 and fill densely from slot 0 (no cross-XCD
// partial-line sharing). Entry: (src | dst_local<<17, ea bits) = 8 B.

__global__ __launch_bounds__(256) void k_bucket(const int* __restrict__ src,
                                                const int* __restrict__ dst,
                                                const float* __restrict__ ea,
                                                int* __restrict__ bcur,
                                                uint2* __restrict__ tmp) {
    const int r = blockIdx.x & 7;
    for (int i = blockIdx.x * 256 + threadIdx.x; i < NEDGES; i += gridDim.x * 256) {
        const int d = dst[i];
        const int b = d >> 8;
        const int slot = atomicAdd(&bcur[r * NB + b], 1);
        const unsigned w = (unsigned)src[i] | ((unsigned)(d & 255) << 17);
        tmp[(size_t)(r * NB + b) * BCAP + slot] = make_uint2(w, __float_as_uint(ea[i]));
    }
}

// Phase B: one block per bucket; reads the 8 replica chunks sequentially and
// places entries at their CSR position. Output window per bucket ~32 KB,
// written by a single block -> single L2 -> full-line writebacks.

__global__ __launch_bounds__(256) void k_place(const uint2* __restrict__ tmp,
                                               const int* __restrict__ bcur,
                                               const int* __restrict__ rowptr,
                                               int* __restrict__ cursor,
                                               uint2* __restrict__ edata) {
    const int b = blockIdx.x;
    for (int r = 0; r < 8; ++r) {
        const int n = bcur[r * NB + b];
        const uint2* chunk = &tmp[(size_t)(r * NB + b) * BCAP];
        for (int j = threadIdx.x; j < n; j += 256) {
            const uint2 e = chunk[j];
            const int d = (b << 8) + (int)((e.x >> 17) & 255u);
            const int pos = rowptr[d] + atomicAdd(&cursor[d], 1);
            edata[pos] = make_uint2(e.x & 0x1FFFFu, e.y);
        }
    }
}

// ---------------- register-tiled dual GEMM: [XL|XR] = X @ [Wl|Wr] + [bl|br] ----------------

template <int K>
__global__ __launch_bounds__(256) void k_gemm(const float* __restrict__ X,
                                              const float* __restrict__ Wl,
                                              const float* __restrict__ bl,
                                              const float* __restrict__ Wr,
                                              const float* __restrict__ br,
                                              float* __restrict__ XL,
                                              float* __restrict__ XR) {
    constexpr int KC = 32;
    __shared__ float sX[KC][132];
    __shared__ float sW[KC][128];
    const int t = threadIdx.x;
    const int tc = t & 15, tr = t >> 4;
    const int r0 = blockIdx.x * 128;

    float acc[8][8] = {};

    for (int kc = 0; kc < K; kc += KC) {
#pragma unroll
        for (int i = 0; i < 4; ++i) {
            int l = t + 256 * i;
            int row = l >> 3;
            int kq = (l & 7) * 4;
            int rr = min(r0 + row, NNODES - 1);
            const float4 v = *(const float4*)&X[(size_t)rr * K + kc + kq];
            sX[kq + 0][row] = v.x;
            sX[kq + 1][row] = v.y;
            sX[kq + 2][row] = v.z;
            sX[kq + 3][row] = v.w;
        }
#pragma unroll
        for (int i = 0; i < 4; ++i) {
            int l = t + 256 * i;
            int k = l >> 5;
            int cq = l & 31;
            const float* sp = (cq < 16) ? &Wl[(size_t)(kc + k) * 64 + cq * 4]
                                        : &Wr[(size_t)(kc + k) * 64 + (cq - 16) * 4];
            *(float4*)&sW[k][cq * 4] = *(const float4*)sp;
        }
        __syncthreads();
#pragma unroll 4
        for (int k = 0; k < KC; ++k) {
            float xf[8], wf[8];
            *(float4*)&xf[0] = *(const float4*)&sX[k][tr * 8];
            *(float4*)&xf[4] = *(const float4*)&sX[k][tr * 8 + 4];
            *(float4*)&wf[0] = *(const float4*)&sW[k][tc * 8];
            *(float4*)&wf[4] = *(const float4*)&sW[k][tc * 8 + 4];
#pragma unroll
            for (int i2 = 0; i2 < 8; ++i2)
#pragma unroll
                for (int j = 0; j < 8; ++j)
                    acc[i2][j] += xf[i2] * wf[j];
        }
        __syncthreads();
    }

    const bool isL = (tc < 8);
    const int cb = isL ? tc * 8 : tc * 8 - 64;
    const float* bb = isL ? bl : br;
    float* OUT = isL ? XL : XR;
    float4 b0 = *(const float4*)&bb[cb];
    float4 b1 = *(const float4*)&bb[cb + 4];
#pragma unroll
    for (int i = 0; i < 8; ++i) {
        int row = r0 + tr * 8 + i;
        if (row < NNODES) {
            float4 v0 = {acc[i][0] + b0.x, acc[i][1] + b0.y, acc[i][2] + b0.z, acc[i][3] + b0.w};
            float4 v1 = {acc[i][4] + b1.x, acc[i][5] + b1.y, acc[i][6] + b1.z, acc[i][7] + b1.w};
            *(float4*)&OUT[(size_t)row * 64 + cb] = v0;
            *(float4*)&OUT[(size_t)row * 64 + cb + 4] = v1;
        }
    }
}

// ---------------- fused GATv2 edge pass ----------------
// One wave per node. lane = 16*group + fl; group g handles edge e+g;
// lane holds features [fl*4, fl*4+4) as float4. Online softmax, 4 edges/iter.

__global__ __launch_bounds__(256) void k_edge(const float* __restrict__ XL,
                                              const float* __restrict__ XR,
                                              const int* __restrict__ rowptr,
                                              const uint2* __restrict__ edata,
                                              const float* __restrict__ We,
                                              const float* __restrict__ att,
                                              const float* __restrict__ bias,
                                              const float* __restrict__ easum,
                                              float* __restrict__ H) {
    const int wave = threadIdx.x >> 6, lane = threadIdx.x & 63;
    const int g = lane >> 4, fl = lane & 15;
    const int fo = fl * 4;
    const float4 We4 = *(const float4*)&We[fo];
    const float4 att4 = *(const float4*)&att[fo];
    const float4 bias4 = *(const float4*)&bias[fo];
    const float ea_mean = easum[0] * (1.0f / NEDGES);

    for (int i = blockIdx.x * 4 + wave; i < NNODES; i += gridDim.x * 4) {
        const float4 xr4 = *(const float4*)&XR[(size_t)i * 64 + fo];
        const float4 xl4 = *(const float4*)&XL[(size_t)i * 64 + fo];

        float mx = xl4.x + xr4.x + ea_mean * We4.x;
        float my = xl4.y + xr4.y + ea_mean * We4.y;
        float mz = xl4.z + xr4.z + ea_mean * We4.z;
        float mw = xl4.w + xr4.w + ea_mean * We4.w;
        mx = fmaxf(mx, 0.f) + NEG_SLOPE * fminf(mx, 0.f);
        my = fmaxf(my, 0.f) + NEG_SLOPE * fminf(my, 0.f);
        mz = fmaxf(mz, 0.f) + NEG_SLOPE * fminf(mz, 0.f);
        mw = fmaxf(mw, 0.f) + NEG_SLOPE * fminf(mw, 0.f);
        float part = mx * att4.x + my * att4.y + mz * att4.z + mw * att4.w;
        part += __shfl_xor(part, 1);
        part += __shfl_xor(part, 2);
        part += __shfl_xor(part, 4);
        part += __shfl_xor(part, 8);
        float M = part;
        float S = 1.f;
        float ax = (g == 0) ? xl4.x : 0.f;
        float ay = (g == 0) ? xl4.y : 0.f;
        float az = (g == 0) ? xl4.z : 0.f;
        float aw = (g == 0) ? xl4.w : 0.f;

        const int e0 = rowptr[i], e1 = rowptr[i + 1];
        for (int e = e0; e < e1; e += 4) {
            const int eidx = e + g;
            const bool valid = eidx < e1;
            uint2 se = make_uint2(0u, 0u);
            if (valid) se = edata[eidx];
            const int s = (int)se.x;
            const float eav = __uint_as_float(se.y);
            const float4 v4 = *(const float4*)&XL[(size_t)s * 64 + fo];

            float bx = v4.x + xr4.x + eav * We4.x;
            float by = v4.y + xr4.y + eav * We4.y;
            float bz = v4.z + xr4.z + eav * We4.z;
            float bw = v4.w + xr4.w + eav * We4.w;
            bx = fmaxf(bx, 0.f) + NEG_SLOPE * fminf(bx, 0.f);
            by = fmaxf(by, 0.f) + NEG_SLOPE * fminf(by, 0.f);
            bz = fmaxf(bz, 0.f) + NEG_SLOPE * fminf(bz, 0.f);
            bw = fmaxf(bw, 0.f) + NEG_SLOPE * fminf(bw, 0.f);
            float d = bx * att4.x + by * att4.y + bz * att4.z + bw * att4.w;
            d += __shfl_xor(d, 1);
            d += __shfl_xor(d, 2);
            d += __shfl_xor(d, 4);
            d += __shfl_xor(d, 8);
            float a = valid ? d : -1e30f;

            float am = fmaxf(a, __shfl_xor(a, 16));
            am = fmaxf(am, __shfl_xor(am, 32));
            const float newM = fmaxf(M, am);
            const float sc = __expf(M - newM);
            const float p = __expf(a - newM);
            float ps = p;
            ps += __shfl_xor(ps, 16);
            ps += __shfl_xor(ps, 32);
            S = S * sc + ps;
            ax = ax * sc + p * v4.x;
            ay = ay * sc + p * v4.y;
            az = az * sc + p * v4.z;
            aw = aw * sc + p * v4.w;
            M = newM;
        }

        ax += __shfl_xor(ax, 16); ax += __shfl_xor(ax, 32);
        ay += __shfl_xor(ay, 16); ay += __shfl_xor(ay, 32);
        az += __shfl_xor(az, 16); az += __shfl_xor(az, 32);
        aw += __shfl_xor(aw, 16); aw += __shfl_xor(aw, 32);

        if (g == 0) {
            const float invS = 1.0f / S;
            float4 o;
            o.x = fmaxf(ax * invS + bias4.x, 0.f);
            o.y = fmaxf(ay * invS + bias4.y, 0.f);
            o.z = fmaxf(az * invS + bias4.z, 0.f);
            o.w = fmaxf(aw * invS + bias4.w, 0.f);
            *(float4*)&H[(size_t)i * 64 + fo] = o;
        }
    }
}

// ---------------- tail: mean pool + linear + softmax ----------------

__global__ __launch_bounds__(256) void k_colsum(const float* __restrict__ H,
                                                float* __restrict__ gsum) {
    int wave = threadIdx.x >> 6, lane = threadIdx.x & 63;
    float s = 0.f;
    for (int r = blockIdx.x * 4 + wave; r < NNODES; r += gridDim.x * 4)
        s += H[(size_t)r * 64 + lane];
    __shared__ float ls[4][64];
    ls[wave][lane] = s;
    __syncthreads();
    if (wave == 0) {
        s = ls[0][lane] + ls[1][lane] + ls[2][lane] + ls[3][lane];
        atomicAdd(&gsum[lane], s);
    }
}

__global__ __launch_bounds__(64) void k_head(const float* __restrict__ gsum,
                                             const float* __restrict__ Wlin,
                                             const float* __restrict__ blin,
                                             float* __restrict__ out) {
    int lane = threadIdx.x;
    float g = gsum[lane] * (1.0f / NNODES);
    float a0 = wave_sum64(g * Wlin[lane * 2 + 0]);
    float a1 = wave_sum64(g * Wlin[lane * 2 + 1]);
    if (lane == 0) {
        float l0 = a0 + blin[0], l1 = a1 + blin[1];
        float mx = fmaxf(l0, l1);
        float e0 = __expf(l0 - mx), e1 = __expf(l1 - mx);
        float inv = 1.f / (e0 + e1);
        out[0] = e0 * inv;
        out[1] = e1 * inv;
    }
}

extern "C" void kernel_launch(void* const* d_in, const int* in_sizes, int n_in,
                              void* d_out, int out_size, void* d_ws, size_t ws_size,
                              hipStream_t stream) {
    const float* x = (const float*)d_in[0];
    const int* ei = (const int*)d_in[1];
    const float* ea = (const float*)d_in[2];
    const int* src = ei;
    const int* dst = ei + NEDGES;
    auto W = [&](int i) { return (const float*)d_in[i]; };

    char* ws = (char*)d_ws;
    size_t off = 0;
    auto alloc = [&](size_t bytes) {
        void* p = ws + off;
        off += (bytes + 255) & ~(size_t)255;
        return p;
    };
    float* XLb = (float*)alloc((size_t)NNODES * 64 * 4);
    float* XRb = (float*)alloc((size_t)NNODES * 64 * 4);
    float* Hb = (float*)alloc((size_t)NNODES * 64 * 4);
    int* rowptr = (int*)alloc((size_t)(NNODES + 1) * 4);
    int* cnt = (int*)alloc((size_t)NNODES * 4);
    uint2* edata = (uint2*)alloc((size_t)NEDGES * 8);
    float* easum = (float*)alloc(4);
    float* gsum = (float*)alloc(64 * 4);
    int* bsum = (int*)alloc((size_t)SCAN_BLOCKS * 4);
    int* boff = (int*)alloc((size_t)SCAN_BLOCKS * 4);
    int* bcur = (int*)alloc((size_t)8 * NB * 4);
    uint2* tmp = (uint2*)Hb;  // 8*NB*BCAP*8B = 25.02 MB <= Hb's 25.6 MB; Hb dead until layer-1 k_edge

    hipMemsetAsync(cnt, 0, (size_t)NNODES * 4, stream);
    hipMemsetAsync(easum, 0, 4, stream);
    hipMemsetAsync(gsum, 0, 64 * 4, stream);
    hipMemsetAsync(bcur, 0, (size_t)8 * NB * 4, stream);

    k_hist<<<2048, 256, 0, stream>>>(dst, ea, cnt, easum);
    k_partial<<<SCAN_BLOCKS, 256, 0, stream>>>(cnt, bsum);
    k_scanb<<<1, 512, 0, stream>>>(bsum, boff, rowptr);
    k_scanfin<<<SCAN_BLOCKS, 256, 0, stream>>>(cnt, boff, rowptr);
    k_bucket<<<2048, 256, 0, stream>>>(src, dst, ea, bcur, tmp);
    hipMemsetAsync(cnt, 0, (size_t)NNODES * 4, stream);  // reuse as per-node cursor
    k_place<<<NB, 256, 0, stream>>>(tmp, bcur, rowptr, cnt, edata);

    int gemm_grid = (NNODES + 127) / 128;
    int edge_grid = (NNODES + 3) / 4;

    k_gemm<128><<<gemm_grid, 256, 0, stream>>>(x, W(3), W(4), W(5), W(6), XLb, XRb);
    k_edge<<<edge_grid, 256, 0, stream>>>(XLb, XRb, rowptr, edata,
                                          W(7), W(8), W(9), easum, Hb);
    k_gemm<64><<<gemm_grid, 256, 0, stream>>>(Hb, W(10), W(11), W(12), W(13), XLb, XRb);
    k_edge<<<edge_grid, 256, 0, stream>>>(XLb, XRb, rowptr, edata,
                                          W(14), W(15), W(16), easum, Hb);
    k_gemm<64><<<gemm_grid, 256, 0, stream>>>(Hb, W(17), W(18), W(19), W(20), XLb, XRb);
    k_edge<<<edge_grid, 256, 0, stream>>>(XLb, XRb, rowptr, edata,
                                          W(21), W(22), W(23), easum, Hb);

    k_colsum<<<1024, 256, 0, stream>>>(Hb, gsum);
    k_head<<<1, 64, 0, stream>>>(gsum, W(24), W(25), (float*)d_out);
}

// Round 6
// 471.938 us; speedup vs baseline: 1.4511x; 1.4511x over previous
//
#include <hip/hip_runtime.h>
#include <hip/hip_bf16.h>

#define NNODES 100000
#define NEDGES 1600000
#define NEG_SLOPE 0.2f

#define CHUNK 4096
#define EPT 16                                  // edges per thread in k_lsort
#define NBLK ((NEDGES + CHUNK - 1) / CHUNK)     // 391 sort blocks
#define NB ((NNODES + 255) / 256)               // 391 buckets (256 nodes each)
#define FLATN (NB * NBLK)                       // 152881
#define SCB ((FLATN + 255) / 256)               // 598
#define FCAP 5632                               // bucket entry cap (mean 4092, +24 sigma)

__device__ __forceinline__ float wave_sum64(float v) {
#pragma unroll
    for (int off = 1; off < 64; off <<= 1) v += __shfl_xor(v, off, 64);
    return v;
}

__device__ __forceinline__ int wave_sum64i(int v) {
#pragma unroll
    for (int off = 1; off < 64; off <<= 1) v += __shfl_xor(v, off, 64);
    return v;
}

// ---------------- phase A: per-chunk counting sort by bucket (all-coalesced) ----------------

__global__ __launch_bounds__(256) void k_lsort(const int* __restrict__ src,
                                               const int* __restrict__ dst,
                                               const float* __restrict__ ea,
                                               uint2* __restrict__ tmps,
                                               int* __restrict__ gcnt,
                                               int* __restrict__ lscan,
                                               float* __restrict__ easum) {
    __shared__ uint2 ent[CHUNK];                 // 32 KB
    __shared__ unsigned short perm[CHUNK];       // 8 KB
    __shared__ int hist[NB];
    __shared__ int cur[NB];
    __shared__ float ws[4];
    const int t = threadIdx.x;
    const int j = blockIdx.x;
    const int base = j * CHUNK;
    const int n = min(CHUNK, NEDGES - base);

    for (int b = t; b < NB; b += 256) hist[b] = 0;
    __syncthreads();

    int bkt[EPT];
    float s = 0.f;
#pragma unroll
    for (int k = 0; k < EPT; ++k) {
        const int l = t + k * 256;
        bkt[k] = -1;
        if (l < n) {
            const int i = base + l;
            const int d = dst[i];
            const float e = ea[i];
            const int b = d >> 8;
            bkt[k] = b;
            ent[l] = make_uint2((unsigned)src[i] | ((unsigned)(d & 255) << 17),
                                __float_as_uint(e));
            atomicAdd(&hist[b], 1);
            s += e;
        }
    }
    s = wave_sum64(s);
    if ((t & 63) == 0) ws[t >> 6] = s;
    __syncthreads();
    if (t == 0) atomicAdd(easum, ws[0] + ws[1] + ws[2] + ws[3]);

    // exclusive scan of hist[0..NB) -> cur, wave 0 only (56 lanes x 7 elems)
    if (t < 64) {
        int x[7];
        int run = 0;
#pragma unroll
        for (int q = 0; q < 7; ++q) {
            const int idx = t * 7 + q;
            x[q] = (idx < NB) ? hist[idx] : 0;
            run += x[q];
        }
        int inc = run;
#pragma unroll
        for (int o = 1; o < 64; o <<= 1) {
            int u = __shfl_up(inc, o, 64);
            if (t >= o) inc += u;
        }
        int r = inc - run;   // lane-exclusive
#pragma unroll
        for (int q = 0; q < 7; ++q) {
            const int idx = t * 7 + q;
            if (idx < NB) cur[idx] = r;
            r += x[q];
        }
    }
    __syncthreads();

#pragma unroll
    for (int k = 0; k < EPT; ++k) {
        if (bkt[k] >= 0) {
            const int r = atomicAdd(&cur[bkt[k]], 1);
            perm[r] = (unsigned short)(t + k * 256);
        }
    }
    __syncthreads();

    for (int o = t; o < n; o += 256)
        tmps[base + o] = ent[perm[o]];           // coalesced global write
    for (int b = t; b < NB; b += 256) {
        gcnt[b * NBLK + j] = hist[b];            // bucket-major (for flat scan)
        lscan[j * NB + b] = cur[b] - hist[b];    // local exclusive offset
    }
}

// ---------------- flat exclusive scan of gcnt[FLATN] -> goff ----------------

__global__ __launch_bounds__(256) void k_part2(const int* __restrict__ v, int n,
                                               int* __restrict__ bsum) {
    int i = blockIdx.x * 256 + threadIdx.x;
    int x = (i < n) ? v[i] : 0;
    x = wave_sum64i(x);
    __shared__ int wsh[4];
    if ((threadIdx.x & 63) == 0) wsh[threadIdx.x >> 6] = x;
    __syncthreads();
    if (threadIdx.x == 0) bsum[blockIdx.x] = wsh[0] + wsh[1] + wsh[2] + wsh[3];
}

__global__ __launch_bounds__(1024) void k_scanb2(const int* __restrict__ bsum, int nb,
                                                 int* __restrict__ boff,
                                                 int* __restrict__ rowptr) {
    __shared__ int sh[1024];
    int t = threadIdx.x;
    int v = (t < nb) ? bsum[t] : 0;
    sh[t] = v;
    __syncthreads();
    for (int off = 1; off < 1024; off <<= 1) {
        int u = (t >= off) ? sh[t - off] : 0;
        __syncthreads();
        sh[t] += u;
        __syncthreads();
    }
    if (t < nb) boff[t] = sh[t] - v;
    if (t == 0) rowptr[NNODES] = NEDGES;
}

__global__ __launch_bounds__(256) void k_scanfin2(const int* __restrict__ v, int n,
                                                  const int* __restrict__ boff,
                                                  int* __restrict__ out) {
    int t = threadIdx.x, lane = t & 63, wave = t >> 6;
    int i = blockIdx.x * 256 + t;
    int x = (i < n) ? v[i] : 0;
    int orig = x;
#pragma unroll
    for (int off = 1; off < 64; off <<= 1) {
        int u = __shfl_up(x, off, 64);
        if (lane >= off) x += u;
    }
    __shared__ int wsh[4];
    if (lane == 63) wsh[wave] = x;
    __syncthreads();
    int wexc = 0;
    for (int w = 0; w < wave; ++w) wexc += wsh[w];
    if (i < n) out[i] = boff[blockIdx.x] + wexc + x - orig;
}

// ---------------- phase C: per-bucket gather + LDS counting sort by node ----------------

__global__ __launch_bounds__(256) void k_fsort(const uint2* __restrict__ tmps,
                                               const int* __restrict__ lscan,
                                               const int* __restrict__ goff,
                                               int* __restrict__ rowptr,
                                               uint2* __restrict__ edata) {
    __shared__ uint2 ent[FCAP];                  // 44 KB
    __shared__ unsigned short perm[FCAP];        // 11 KB
    __shared__ int joff[NBLK + 1];
    __shared__ int jsrc[NBLK];
    __shared__ int hist[256];
    __shared__ int cur[256];
    const int b = blockIdx.x;
    const int t = threadIdx.x;
    const int base = goff[b * NBLK];             // bucket base position in edata

    for (int q = t; q < 256; q += 256) hist[q] = 0;
    for (int j = t; j < NBLK; j += 256) {
        joff[j] = goff[b * NBLK + j] - base;
        jsrc[j] = j * CHUNK + lscan[j * NB + b];
    }
    if (t == 0) joff[NBLK] = ((b == NB - 1) ? NEDGES : goff[(b + 1) * NBLK]) - base;
    __syncthreads();
    const int T = min(joff[NBLK], FCAP);

    for (int idx = t; idx < T; idx += 256) {
        int lo = 0, hi = NBLK;
        while (hi - lo > 1) { int mid = (lo + hi) >> 1; if (joff[mid] <= idx) lo = mid; else hi = mid; }
        const uint2 e = tmps[jsrc[lo] + (idx - joff[lo])];   // piecewise-coalesced
        ent[idx] = e;
        atomicAdd(&hist[(e.x >> 17) & 255u], 1);
    }
    __syncthreads();

    // exclusive scan hist[0..256) -> cur, wave 0 (64 lanes x 4)
    if (t < 64) {
        int x[4];
        int run = 0;
#pragma unroll
        for (int q = 0; q < 4; ++q) { x[q] = hist[t * 4 + q]; run += x[q]; }
        int inc = run;
#pragma unroll
        for (int o = 1; o < 64; o <<= 1) {
            int u = __shfl_up(inc, o, 64);
            if (t >= o) inc += u;
        }
        int r = inc - run;
#pragma unroll
        for (int q = 0; q < 4; ++q) { cur[t * 4 + q] = r; r += x[q]; }
    }
    __syncthreads();

    {
        const int i = b * 256 + t;
        if (i < NNODES) rowptr[i] = base + cur[t];
    }
    __syncthreads();    // rowptr reads of cur must complete before rank mutation

    for (int idx = t; idx < T; idx += 256) {
        const int d = (int)((ent[idx].x >> 17) & 255u);
        const int r = atomicAdd(&cur[d], 1);
        perm[r] = (unsigned short)idx;
    }
    __syncthreads();
    for (int k = t; k < T; k += 256)
        edata[base + k] = ent[perm[k]];          // coalesced global write
}

// ---------------- register-tiled dual GEMM: [XL|XR] = X @ [Wl|Wr] + [bl|br] ----------------

template <int K>
__global__ __launch_bounds__(256) void k_gemm(const float* __restrict__ X,
                                              const float* __restrict__ Wl,
                                              const float* __restrict__ bl,
                                              const float* __restrict__ Wr,
                                              const float* __restrict__ br,
                                              float* __restrict__ XL,
                                              float* __restrict__ XR) {
    constexpr int KC = 32;
    __shared__ float sX[KC][132];
    __shared__ float sW[KC][128];
    const int t = threadIdx.x;
    const int tc = t & 15, tr = t >> 4;
    const int r0 = blockIdx.x * 128;

    float acc[8][8] = {};

    for (int kc = 0; kc < K; kc += KC) {
#pragma unroll
        for (int i = 0; i < 4; ++i) {
            int l = t + 256 * i;
            int row = l >> 3;
            int kq = (l & 7) * 4;
            int rr = min(r0 + row, NNODES - 1);
            const float4 v = *(const float4*)&X[(size_t)rr * K + kc + kq];
            sX[kq + 0][row] = v.x;
            sX[kq + 1][row] = v.y;
            sX[kq + 2][row] = v.z;
            sX[kq + 3][row] = v.w;
        }
#pragma unroll
        for (int i = 0; i < 4; ++i) {
            int l = t + 256 * i;
            int k = l >> 5;
            int cq = l & 31;
            const float* sp = (cq < 16) ? &Wl[(size_t)(kc + k) * 64 + cq * 4]
                                        : &Wr[(size_t)(kc + k) * 64 + (cq - 16) * 4];
            *(float4*)&sW[k][cq * 4] = *(const float4*)sp;
        }
        __syncthreads();
#pragma unroll 4
        for (int k = 0; k < KC; ++k) {
            float xf[8], wf[8];
            *(float4*)&xf[0] = *(const float4*)&sX[k][tr * 8];
            *(float4*)&xf[4] = *(const float4*)&sX[k][tr * 8 + 4];
            *(float4*)&wf[0] = *(const float4*)&sW[k][tc * 8];
            *(float4*)&wf[4] = *(const float4*)&sW[k][tc * 8 + 4];
#pragma unroll
            for (int i2 = 0; i2 < 8; ++i2)
#pragma unroll
                for (int j = 0; j < 8; ++j)
                    acc[i2][j] += xf[i2] * wf[j];
        }
        __syncthreads();
    }

    const bool isL = (tc < 8);
    const int cb = isL ? tc * 8 : tc * 8 - 64;
    const float* bb = isL ? bl : br;
    float* OUT = isL ? XL : XR;
    float4 b0 = *(const float4*)&bb[cb];
    float4 b1 = *(const float4*)&bb[cb + 4];
#pragma unroll
    for (int i = 0; i < 8; ++i) {
        int row = r0 + tr * 8 + i;
        if (row < NNODES) {
            float4 v0 = {acc[i][0] + b0.x, acc[i][1] + b0.y, acc[i][2] + b0.z, acc[i][3] + b0.w};
            float4 v1 = {acc[i][4] + b1.x, acc[i][5] + b1.y, acc[i][6] + b1.z, acc[i][7] + b1.w};
            *(float4*)&OUT[(size_t)row * 64 + cb] = v0;
            *(float4*)&OUT[(size_t)row * 64 + cb + 4] = v1;
        }
    }
}

// ---------------- fused GATv2 edge pass ----------------
// One wave per node. lane = 16*group + fl; group g handles edge e+g;
// lane holds features [fl*4, fl*4+4) as float4. Online softmax, 4 edges/iter.

__global__ __launch_bounds__(256) void k_edge(const float* __restrict__ XL,
                                              const float* __restrict__ XR,
                                              const int* __restrict__ rowptr,
                                              const uint2* __restrict__ edata,
                                              const float* __restrict__ We,
                                              const float* __restrict__ att,
                                              const float* __restrict__ bias,
                                              const float* __restrict__ easum,
                                              float* __restrict__ H) {
    const int wave = threadIdx.x >> 6, lane = threadIdx.x & 63;
    const int g = lane >> 4, fl = lane & 15;
    const int fo = fl * 4;
    const float4 We4 = *(const float4*)&We[fo];
    const float4 att4 = *(const float4*)&att[fo];
    const float4 bias4 = *(const float4*)&bias[fo];
    const float ea_mean = easum[0] * (1.0f / NEDGES);

    for (int i = blockIdx.x * 4 + wave; i < NNODES; i += gridDim.x * 4) {
        const float4 xr4 = *(const float4*)&XR[(size_t)i * 64 + fo];
        const float4 xl4 = *(const float4*)&XL[(size_t)i * 64 + fo];

        float mx = xl4.x + xr4.x + ea_mean * We4.x;
        float my = xl4.y + xr4.y + ea_mean * We4.y;
        float mz = xl4.z + xr4.z + ea_mean * We4.z;
        float mw = xl4.w + xr4.w + ea_mean * We4.w;
        mx = fmaxf(mx, 0.f) + NEG_SLOPE * fminf(mx, 0.f);
        my = fmaxf(my, 0.f) + NEG_SLOPE * fminf(my, 0.f);
        mz = fmaxf(mz, 0.f) + NEG_SLOPE * fminf(mz, 0.f);
        mw = fmaxf(mw, 0.f) + NEG_SLOPE * fminf(mw, 0.f);
        float part = mx * att4.x + my * att4.y + mz * att4.z + mw * att4.w;
        part += __shfl_xor(part, 1);
        part += __shfl_xor(part, 2);
        part += __shfl_xor(part, 4);
        part += __shfl_xor(part, 8);
        float M = part;
        float S = 1.f;
        float ax = (g == 0) ? xl4.x : 0.f;
        float ay = (g == 0) ? xl4.y : 0.f;
        float az = (g == 0) ? xl4.z : 0.f;
        float aw = (g == 0) ? xl4.w : 0.f;

        const int e0 = rowptr[i], e1 = rowptr[i + 1];
        for (int e = e0; e < e1; e += 4) {
            const int eidx = e + g;
            const bool valid = eidx < e1;
            uint2 se = make_uint2(0u, 0u);
            if (valid) se = edata[eidx];
            const int s = (int)(se.x & 0x1FFFFu);
            const float eav = __uint_as_float(se.y);
            const float4 v4 = *(const float4*)&XL[(size_t)s * 64 + fo];

            float bx = v4.x + xr4.x + eav * We4.x;
            float by = v4.y + xr4.y + eav * We4.y;
            float bz = v4.z + xr4.z + eav * We4.z;
            float bw = v4.w + xr4.w + eav * We4.w;
            bx = fmaxf(bx, 0.f) + NEG_SLOPE * fminf(bx, 0.f);
            by = fmaxf(by, 0.f) + NEG_SLOPE * fminf(by, 0.f);
            bz = fmaxf(bz, 0.f) + NEG_SLOPE * fminf(bz, 0.f);
            bw = fmaxf(bw, 0.f) + NEG_SLOPE * fminf(bw, 0.f);
            float d = bx * att4.x + by * att4.y + bz * att4.z + bw * att4.w;
            d += __shfl_xor(d, 1);
            d += __shfl_xor(d, 2);
            d += __shfl_xor(d, 4);
            d += __shfl_xor(d, 8);
            float a = valid ? d : -1e30f;

            float am = fmaxf(a, __shfl_xor(a, 16));
            am = fmaxf(am, __shfl_xor(am, 32));
            const float newM = fmaxf(M, am);
            const float sc = __expf(M - newM);
            const float p = __expf(a - newM);
            float ps = p;
            ps += __shfl_xor(ps, 16);
            ps += __shfl_xor(ps, 32);
            S = S * sc + ps;
            ax = ax * sc + p * v4.x;
            ay = ay * sc + p * v4.y;
            az = az * sc + p * v4.z;
            aw = aw * sc + p * v4.w;
            M = newM;
        }

        ax += __shfl_xor(ax, 16); ax += __shfl_xor(ax, 32);
        ay += __shfl_xor(ay, 16); ay += __shfl_xor(ay, 32);
        az += __shfl_xor(az, 16); az += __shfl_xor(az, 32);
        aw += __shfl_xor(aw, 16); aw += __shfl_xor(aw, 32);

        if (g == 0) {
            const float invS = 1.0f / S;
            float4 o;
            o.x = fmaxf(ax * invS + bias4.x, 0.f);
            o.y = fmaxf(ay * invS + bias4.y, 0.f);
            o.z = fmaxf(az * invS + bias4.z, 0.f);
            o.w = fmaxf(aw * invS + bias4.w, 0.f);
            *(float4*)&H[(size_t)i * 64 + fo] = o;
        }
    }
}

// ---------------- tail: mean pool + linear + softmax ----------------

__global__ __launch_bounds__(256) void k_colsum(const float* __restrict__ H,
                                                float* __restrict__ gsum) {
    int wave = threadIdx.x >> 6, lane = threadIdx.x & 63;
    float s = 0.f;
    for (int r = blockIdx.x * 4 + wave; r < NNODES; r += gridDim.x * 4)
        s += H[(size_t)r * 64 + lane];
    __shared__ float ls[4][64];
    ls[wave][lane] = s;
    __syncthreads();
    if (wave == 0) {
        s = ls[0][lane] + ls[1][lane] + ls[2][lane] + ls[3][lane];
        atomicAdd(&gsum[lane], s);
    }
}

__global__ __launch_bounds__(64) void k_head(const float* __restrict__ gsum,
                                             const float* __restrict__ Wlin,
                                             const float* __restrict__ blin,
                                             float* __restrict__ out) {
    int lane = threadIdx.x;
    float g = gsum[lane] * (1.0f / NNODES);
    float a0 = wave_sum64(g * Wlin[lane * 2 + 0]);
    float a1 = wave_sum64(g * Wlin[lane * 2 + 1]);
    if (lane == 0) {
        float l0 = a0 + blin[0], l1 = a1 + blin[1];
        float mx = fmaxf(l0, l1);
        float e0 = __expf(l0 - mx), e1 = __expf(l1 - mx);
        float inv = 1.f / (e0 + e1);
        out[0] = e0 * inv;
        out[1] = e1 * inv;
    }
}

extern "C" void kernel_launch(void* const* d_in, const int* in_sizes, int n_in,
                              void* d_out, int out_size, void* d_ws, size_t ws_size,
                              hipStream_t stream) {
    const float* x = (const float*)d_in[0];
    const int* ei = (const int*)d_in[1];
    const float* ea = (const float*)d_in[2];
    const int* src = ei;
    const int* dst = ei + NEDGES;
    auto W = [&](int i) { return (const float*)d_in[i]; };

    char* ws = (char*)d_ws;
    size_t off = 0;
    auto alloc = [&](size_t bytes) {
        void* p = ws + off;
        off += (bytes + 255) & ~(size_t)255;
        return p;
    };
    float* XLb = (float*)alloc((size_t)NNODES * 64 * 4);
    float* XRb = (float*)alloc((size_t)NNODES * 64 * 4);
    float* Hb = (float*)alloc((size_t)NNODES * 64 * 4);
    int* rowptr = (int*)alloc((size_t)(NNODES + 1) * 4);
    uint2* edata = (uint2*)alloc((size_t)NEDGES * 8);
    float* easum = (float*)alloc(4);
    float* gsum = (float*)alloc(64 * 4);
    int* gcnt = (int*)alloc((size_t)FLATN * 4);
    int* lscan = (int*)alloc((size_t)FLATN * 4);
    int* goff = (int*)alloc((size_t)FLATN * 4);
    int* part2 = (int*)alloc((size_t)SCB * 4);
    int* boff2 = (int*)alloc((size_t)SCB * 4);
    uint2* tmps = (uint2*)Hb;  // NBLK*CHUNK*8 = 12.8 MB <= Hb's 25.6 MB; Hb dead until layer-1 k_edge

    hipMemsetAsync(easum, 0, 4, stream);
    hipMemsetAsync(gsum, 0, 64 * 4, stream);

    k_lsort<<<NBLK, 256, 0, stream>>>(src, dst, ea, tmps, gcnt, lscan, easum);
    k_part2<<<SCB, 256, 0, stream>>>(gcnt, FLATN, part2);
    k_scanb2<<<1, 1024, 0, stream>>>(part2, SCB, boff2, rowptr);
    k_scanfin2<<<SCB, 256, 0, stream>>>(gcnt, FLATN, boff2, goff);
    k_fsort<<<NB, 256, 0, stream>>>(tmps, lscan, goff, rowptr, edata);

    int gemm_grid = (NNODES + 127) / 128;
    int edge_grid = (NNODES + 3) / 4;

    k_gemm<128><<<gemm_grid, 256, 0, stream>>>(x, W(3), W(4), W(5), W(6), XLb, XRb);
    k_edge<<<edge_grid, 256, 0, stream>>>(XLb, XRb, rowptr, edata,
                                          W(7), W(8), W(9), easum, Hb);
    k_gemm<64><<<gemm_grid, 256, 0, stream>>>(Hb, W(10), W(11), W(12), W(13), XLb, XRb);
    k_edge<<<edge_grid, 256, 0, stream>>>(XLb, XRb, rowptr, edata,
                                          W(14), W(15), W(16), easum, Hb);
    k_gemm<64><<<gemm_grid, 256, 0, stream>>>(Hb, W(17), W(18), W(19), W(20), XLb, XRb);
    k_edge<<<edge_grid, 256, 0, stream>>>(XLb, XRb, rowptr, edata,
                                          W(21), W(22), W(23), easum, Hb);

    k_colsum<<<1024, 256, 0, stream>>>(Hb, gsum);
    k_head<<<1, 64, 0, stream>>>(gsum, W(24), W(25), (float*)d_out);
}

// Round 7
// 469.138 us; speedup vs baseline: 1.4598x; 1.0060x over previous
//
#include <hip/hip_runtime.h>
#include <hip/hip_bf16.h>

#define NNODES 100000
#define NEDGES 1600000
#define NEG_SLOPE 0.2f

#define CHUNK 4096
#define EPT 16                                  // edges per thread in k_lsort
#define NBLK ((NEDGES + CHUNK - 1) / CHUNK)     // 391 sort blocks
#define NB ((NNODES + 255) / 256)               // 391 buckets (256 nodes each)
#define FLATN (NB * NBLK)                       // 152881
#define SCB ((FLATN + 255) / 256)               // 598
#define FCAP 5632                               // bucket entry cap (mean 4092, +24 sigma)

__device__ __forceinline__ float wave_sum64(float v) {
#pragma unroll
    for (int off = 1; off < 64; off <<= 1) v += __shfl_xor(v, off, 64);
    return v;
}

__device__ __forceinline__ int wave_sum64i(int v) {
#pragma unroll
    for (int off = 1; off < 64; off <<= 1) v += __shfl_xor(v, off, 64);
    return v;
}

// pack two f32 -> one uint of 2 bf16 (RNE)
__device__ __forceinline__ unsigned pack_bf2(float a, float b) {
    unsigned ua = __float_as_uint(a), ub = __float_as_uint(b);
    ua = (ua + 0x7FFFu + ((ua >> 16) & 1u)) >> 16;
    ub = (ub + 0x7FFFu + ((ub >> 16) & 1u));
    return ua | (ub & 0xFFFF0000u);
}

__device__ __forceinline__ float4 unpack_bf4(uint2 w) {
    float4 r;
    r.x = __uint_as_float(w.x << 16);
    r.y = __uint_as_float(w.x & 0xFFFF0000u);
    r.z = __uint_as_float(w.y << 16);
    r.w = __uint_as_float(w.y & 0xFFFF0000u);
    return r;
}

// ---------------- phase A: per-chunk counting sort by bucket (all-coalesced) ----------------

__global__ __launch_bounds__(256) void k_lsort(const int* __restrict__ src,
                                               const int* __restrict__ dst,
                                               const float* __restrict__ ea,
                                               uint2* __restrict__ tmps,
                                               int* __restrict__ gcnt,
                                               int* __restrict__ lscan,
                                               float* __restrict__ easum) {
    __shared__ uint2 ent[CHUNK];                 // 32 KB
    __shared__ unsigned short perm[CHUNK];       // 8 KB
    __shared__ int hist[NB];
    __shared__ int cur[NB];
    __shared__ float ws[4];
    const int t = threadIdx.x;
    const int j = blockIdx.x;
    const int base = j * CHUNK;
    const int n = min(CHUNK, NEDGES - base);

    for (int b = t; b < NB; b += 256) hist[b] = 0;
    __syncthreads();

    int bkt[EPT];
    float s = 0.f;
#pragma unroll
    for (int k = 0; k < EPT; ++k) {
        const int l = t + k * 256;
        bkt[k] = -1;
        if (l < n) {
            const int i = base + l;
            const int d = dst[i];
            const float e = ea[i];
            const int b = d >> 8;
            bkt[k] = b;
            ent[l] = make_uint2((unsigned)src[i] | ((unsigned)(d & 255) << 17),
                                __float_as_uint(e));
            atomicAdd(&hist[b], 1);
            s += e;
        }
    }
    s = wave_sum64(s);
    if ((t & 63) == 0) ws[t >> 6] = s;
    __syncthreads();
    if (t == 0) atomicAdd(easum, ws[0] + ws[1] + ws[2] + ws[3]);

    // exclusive scan of hist[0..NB) -> cur, wave 0 only (56 lanes x 7 elems)
    if (t < 64) {
        int x[7];
        int run = 0;
#pragma unroll
        for (int q = 0; q < 7; ++q) {
            const int idx = t * 7 + q;
            x[q] = (idx < NB) ? hist[idx] : 0;
            run += x[q];
        }
        int inc = run;
#pragma unroll
        for (int o = 1; o < 64; o <<= 1) {
            int u = __shfl_up(inc, o, 64);
            if (t >= o) inc += u;
        }
        int r = inc - run;   // lane-exclusive
#pragma unroll
        for (int q = 0; q < 7; ++q) {
            const int idx = t * 7 + q;
            if (idx < NB) cur[idx] = r;
            r += x[q];
        }
    }
    __syncthreads();

#pragma unroll
    for (int k = 0; k < EPT; ++k) {
        if (bkt[k] >= 0) {
            const int r = atomicAdd(&cur[bkt[k]], 1);
            perm[r] = (unsigned short)(t + k * 256);
        }
    }
    __syncthreads();

    for (int o = t; o < n; o += 256)
        tmps[base + o] = ent[perm[o]];           // coalesced global write
    for (int b = t; b < NB; b += 256) {
        gcnt[b * NBLK + j] = hist[b];            // bucket-major (for flat scan)
        lscan[j * NB + b] = cur[b] - hist[b];    // local exclusive offset
    }
}

// ---------------- flat exclusive scan of gcnt[FLATN] -> goff ----------------

__global__ __launch_bounds__(256) void k_part2(const int* __restrict__ v, int n,
                                               int* __restrict__ bsum) {
    int i = blockIdx.x * 256 + threadIdx.x;
    int x = (i < n) ? v[i] : 0;
    x = wave_sum64i(x);
    __shared__ int wsh[4];
    if ((threadIdx.x & 63) == 0) wsh[threadIdx.x >> 6] = x;
    __syncthreads();
    if (threadIdx.x == 0) bsum[blockIdx.x] = wsh[0] + wsh[1] + wsh[2] + wsh[3];
}

__global__ __launch_bounds__(1024) void k_scanb2(const int* __restrict__ bsum, int nb,
                                                 int* __restrict__ boff,
                                                 int* __restrict__ rowptr) {
    __shared__ int sh[1024];
    int t = threadIdx.x;
    int v = (t < nb) ? bsum[t] : 0;
    sh[t] = v;
    __syncthreads();
    for (int off = 1; off < 1024; off <<= 1) {
        int u = (t >= off) ? sh[t - off] : 0;
        __syncthreads();
        sh[t] += u;
        __syncthreads();
    }
    if (t < nb) boff[t] = sh[t] - v;
    if (t == 0) rowptr[NNODES] = NEDGES;
}

__global__ __launch_bounds__(256) void k_scanfin2(const int* __restrict__ v, int n,
                                                  const int* __restrict__ boff,
                                                  int* __restrict__ out) {
    int t = threadIdx.x, lane = t & 63, wave = t >> 6;
    int i = blockIdx.x * 256 + t;
    int x = (i < n) ? v[i] : 0;
    int orig = x;
#pragma unroll
    for (int off = 1; off < 64; off <<= 1) {
        int u = __shfl_up(x, off, 64);
        if (lane >= off) x += u;
    }
    __shared__ int wsh[4];
    if (lane == 63) wsh[wave] = x;
    __syncthreads();
    int wexc = 0;
    for (int w = 0; w < wave; ++w) wexc += wsh[w];
    if (i < n) out[i] = boff[blockIdx.x] + wexc + x - orig;
}

// ---------------- phase C: per-bucket gather + LDS counting sort by node ----------------

__global__ __launch_bounds__(256) void k_fsort(const uint2* __restrict__ tmps,
                                               const int* __restrict__ lscan,
                                               const int* __restrict__ goff,
                                               int* __restrict__ rowptr,
                                               uint2* __restrict__ edata) {
    __shared__ uint2 ent[FCAP];                  // 44 KB
    __shared__ unsigned short perm[FCAP];        // 11 KB
    __shared__ int joff[NBLK + 1];
    __shared__ int jsrc[NBLK];
    __shared__ int hist[256];
    __shared__ int cur[256];
    const int b = blockIdx.x;
    const int t = threadIdx.x;
    const int base = goff[b * NBLK];             // bucket base position in edata

    for (int q = t; q < 256; q += 256) hist[q] = 0;
    for (int j = t; j < NBLK; j += 256) {
        joff[j] = goff[b * NBLK + j] - base;
        jsrc[j] = j * CHUNK + lscan[j * NB + b];
    }
    if (t == 0) joff[NBLK] = ((b == NB - 1) ? NEDGES : goff[(b + 1) * NBLK]) - base;
    __syncthreads();
    const int T = min(joff[NBLK], FCAP);

    for (int idx = t; idx < T; idx += 256) {
        int lo = 0, hi = NBLK;
        while (hi - lo > 1) { int mid = (lo + hi) >> 1; if (joff[mid] <= idx) lo = mid; else hi = mid; }
        const uint2 e = tmps[jsrc[lo] + (idx - joff[lo])];   // piecewise-coalesced
        ent[idx] = e;
        atomicAdd(&hist[(e.x >> 17) & 255u], 1);
    }
    __syncthreads();

    // exclusive scan hist[0..256) -> cur, wave 0 (64 lanes x 4)
    if (t < 64) {
        int x[4];
        int run = 0;
#pragma unroll
        for (int q = 0; q < 4; ++q) { x[q] = hist[t * 4 + q]; run += x[q]; }
        int inc = run;
#pragma unroll
        for (int o = 1; o < 64; o <<= 1) {
            int u = __shfl_up(inc, o, 64);
            if (t >= o) inc += u;
        }
        int r = inc - run;
#pragma unroll
        for (int q = 0; q < 4; ++q) { cur[t * 4 + q] = r; r += x[q]; }
    }
    __syncthreads();

    {
        const int i = b * 256 + t;
        if (i < NNODES) rowptr[i] = base + cur[t];
    }
    __syncthreads();    // rowptr reads of cur must complete before rank mutation

    for (int idx = t; idx < T; idx += 256) {
        const int d = (int)((ent[idx].x >> 17) & 255u);
        const int r = atomicAdd(&cur[d], 1);
        perm[r] = (unsigned short)idx;
    }
    __syncthreads();
    for (int k = t; k < T; k += 256)
        edata[base + k] = ent[perm[k]];          // coalesced global write
}

// ---------------- register-tiled dual GEMM: [XL|XR] = X @ [Wl|Wr] + [bl|br] ----------------
// Outputs packed bf16 (2 per uint): row stride 32 uints.

template <int K>
__global__ __launch_bounds__(256) void k_gemm(const float* __restrict__ X,
                                              const float* __restrict__ Wl,
                                              const float* __restrict__ bl,
                                              const float* __restrict__ Wr,
                                              const float* __restrict__ br,
                                              unsigned* __restrict__ XLh,
                                              unsigned* __restrict__ XRh) {
    constexpr int KC = 32;
    __shared__ float sX[KC][132];
    __shared__ float sW[KC][128];
    const int t = threadIdx.x;
    const int tc = t & 15, tr = t >> 4;
    const int r0 = blockIdx.x * 128;

    float acc[8][8] = {};

    for (int kc = 0; kc < K; kc += KC) {
#pragma unroll
        for (int i = 0; i < 4; ++i) {
            int l = t + 256 * i;
            int row = l >> 3;
            int kq = (l & 7) * 4;
            int rr = min(r0 + row, NNODES - 1);
            const float4 v = *(const float4*)&X[(size_t)rr * K + kc + kq];
            sX[kq + 0][row] = v.x;
            sX[kq + 1][row] = v.y;
            sX[kq + 2][row] = v.z;
            sX[kq + 3][row] = v.w;
        }
#pragma unroll
        for (int i = 0; i < 4; ++i) {
            int l = t + 256 * i;
            int k = l >> 5;
            int cq = l & 31;
            const float* sp = (cq < 16) ? &Wl[(size_t)(kc + k) * 64 + cq * 4]
                                        : &Wr[(size_t)(kc + k) * 64 + (cq - 16) * 4];
            *(float4*)&sW[k][cq * 4] = *(const float4*)sp;
        }
        __syncthreads();
#pragma unroll 4
        for (int k = 0; k < KC; ++k) {
            float xf[8], wf[8];
            *(float4*)&xf[0] = *(const float4*)&sX[k][tr * 8];
            *(float4*)&xf[4] = *(const float4*)&sX[k][tr * 8 + 4];
            *(float4*)&wf[0] = *(const float4*)&sW[k][tc * 8];
            *(float4*)&wf[4] = *(const float4*)&sW[k][tc * 8 + 4];
#pragma unroll
            for (int i2 = 0; i2 < 8; ++i2)
#pragma unroll
                for (int j = 0; j < 8; ++j)
                    acc[i2][j] += xf[i2] * wf[j];
        }
        __syncthreads();
    }

    const bool isL = (tc < 8);
    const int cb = isL ? tc * 8 : tc * 8 - 64;
    const float* bb = isL ? bl : br;
    unsigned* OUT = isL ? XLh : XRh;
    float4 b0 = *(const float4*)&bb[cb];
    float4 b1 = *(const float4*)&bb[cb + 4];
#pragma unroll
    for (int i = 0; i < 8; ++i) {
        int row = r0 + tr * 8 + i;
        if (row < NNODES) {
            uint4 v;
            v.x = pack_bf2(acc[i][0] + b0.x, acc[i][1] + b0.y);
            v.y = pack_bf2(acc[i][2] + b0.z, acc[i][3] + b0.w);
            v.z = pack_bf2(acc[i][4] + b1.x, acc[i][5] + b1.y);
            v.w = pack_bf2(acc[i][6] + b1.z, acc[i][7] + b1.w);
            *(uint4*)&OUT[(size_t)row * 32 + (cb >> 1)] = v;
        }
    }
}

// ---------------- fused GATv2 edge pass ----------------
// One wave per node. lane = 16*group + fl; group g handles edge e+g;
// lane holds features [fl*4, fl*4+4) unpacked from bf16 (uint2 = 8 B gather).
// Online softmax with exact deferred rescale, 4 edges/iter.

__global__ __launch_bounds__(256) void k_edge(const uint2* __restrict__ XLh,
                                              const uint2* __restrict__ XRh,
                                              const int* __restrict__ rowptr,
                                              const uint2* __restrict__ edata,
                                              const float* __restrict__ We,
                                              const float* __restrict__ att,
                                              const float* __restrict__ bias,
                                              const float* __restrict__ easum,
                                              float* __restrict__ H) {
    const int wave = threadIdx.x >> 6, lane = threadIdx.x & 63;
    const int g = lane >> 4, fl = lane & 15;
    const int fo = fl * 4;
    const float4 We4 = *(const float4*)&We[fo];
    const float4 att4 = *(const float4*)&att[fo];
    const float4 bias4 = *(const float4*)&bias[fo];
    const float ea_mean = easum[0] * (1.0f / NEDGES);

    for (int i = blockIdx.x * 4 + wave; i < NNODES; i += gridDim.x * 4) {
        const float4 xr4 = unpack_bf4(XRh[(size_t)i * 16 + fl]);
        const float4 xl4 = unpack_bf4(XLh[(size_t)i * 16 + fl]);

        float mx = xl4.x + xr4.x + ea_mean * We4.x;
        float my = xl4.y + xr4.y + ea_mean * We4.y;
        float mz = xl4.z + xr4.z + ea_mean * We4.z;
        float mw = xl4.w + xr4.w + ea_mean * We4.w;
        mx = fmaxf(mx, 0.f) + NEG_SLOPE * fminf(mx, 0.f);
        my = fmaxf(my, 0.f) + NEG_SLOPE * fminf(my, 0.f);
        mz = fmaxf(mz, 0.f) + NEG_SLOPE * fminf(mz, 0.f);
        mw = fmaxf(mw, 0.f) + NEG_SLOPE * fminf(mw, 0.f);
        float part = mx * att4.x + my * att4.y + mz * att4.z + mw * att4.w;
        part += __shfl_xor(part, 1);
        part += __shfl_xor(part, 2);
        part += __shfl_xor(part, 4);
        part += __shfl_xor(part, 8);
        float M = part;
        float S = 1.f;
        float ax = (g == 0) ? xl4.x : 0.f;
        float ay = (g == 0) ? xl4.y : 0.f;
        float az = (g == 0) ? xl4.z : 0.f;
        float aw = (g == 0) ? xl4.w : 0.f;

        const int e0 = rowptr[i], e1 = rowptr[i + 1];
        for (int e = e0; e < e1; e += 4) {
            const int eidx = e + g;
            const bool valid = eidx < e1;
            uint2 se = make_uint2(0u, 0u);
            if (valid) se = edata[eidx];
            const int s = (int)(se.x & 0x1FFFFu);
            const float eav = __uint_as_float(se.y);
            const float4 v4 = unpack_bf4(XLh[(size_t)s * 16 + fl]);

            float bx = v4.x + xr4.x + eav * We4.x;
            float by = v4.y + xr4.y + eav * We4.y;
            float bz = v4.z + xr4.z + eav * We4.z;
            float bw = v4.w + xr4.w + eav * We4.w;
            bx = fmaxf(bx, 0.f) + NEG_SLOPE * fminf(bx, 0.f);
            by = fmaxf(by, 0.f) + NEG_SLOPE * fminf(by, 0.f);
            bz = fmaxf(bz, 0.f) + NEG_SLOPE * fminf(bz, 0.f);
            bw = fmaxf(bw, 0.f) + NEG_SLOPE * fminf(bw, 0.f);
            float d = bx * att4.x + by * att4.y + bz * att4.z + bw * att4.w;
            d += __shfl_xor(d, 1);
            d += __shfl_xor(d, 2);
            d += __shfl_xor(d, 4);
            d += __shfl_xor(d, 8);
            const float a = valid ? d : -1e30f;

            float am = fmaxf(a, __shfl_xor(a, 16));
            am = fmaxf(am, __shfl_xor(am, 32));
            if (am > M) {                         // wave-uniform; exact rescale
                const float sc = __expf(M - am);
                S *= sc; ax *= sc; ay *= sc; az *= sc; aw *= sc;
                M = am;
            }
            const float p = __expf(a - M);        // 0 for invalid groups
            float ps = p;
            ps += __shfl_xor(ps, 16);
            ps += __shfl_xor(ps, 32);
            S += ps;
            ax += p * v4.x;
            ay += p * v4.y;
            az += p * v4.z;
            aw += p * v4.w;
        }

        ax += __shfl_xor(ax, 16); ax += __shfl_xor(ax, 32);
        ay += __shfl_xor(ay, 16); ay += __shfl_xor(ay, 32);
        az += __shfl_xor(az, 16); az += __shfl_xor(az, 32);
        aw += __shfl_xor(aw, 16); aw += __shfl_xor(aw, 32);

        if (g == 0) {
            const float invS = 1.0f / S;
            float4 o;
            o.x = fmaxf(ax * invS + bias4.x, 0.f);
            o.y = fmaxf(ay * invS + bias4.y, 0.f);
            o.z = fmaxf(az * invS + bias4.z, 0.f);
            o.w = fmaxf(aw * invS + bias4.w, 0.f);
            *(float4*)&H[(size_t)i * 64 + fo] = o;
        }
    }
}

// ---------------- tail: mean pool + linear + softmax ----------------

__global__ __launch_bounds__(256) void k_colsum(const float* __restrict__ H,
                                                float* __restrict__ gsum) {
    int wave = threadIdx.x >> 6, lane = threadIdx.x & 63;
    float s = 0.f;
    for (int r = blockIdx.x * 4 + wave; r < NNODES; r += gridDim.x * 4)
        s += H[(size_t)r * 64 + lane];
    __shared__ float ls[4][64];
    ls[wave][lane] = s;
    __syncthreads();
    if (wave == 0) {
        s = ls[0][lane] + ls[1][lane] + ls[2][lane] + ls[3][lane];
        atomicAdd(&gsum[lane], s);
    }
}

__global__ __launch_bounds__(64) void k_head(const float* __restrict__ gsum,
                                             const float* __restrict__ Wlin,
                                             const float* __restrict__ blin,
                                             float* __restrict__ out) {
    int lane = threadIdx.x;
    float g = gsum[lane] * (1.0f / NNODES);
    float a0 = wave_sum64(g * Wlin[lane * 2 + 0]);
    float a1 = wave_sum64(g * Wlin[lane * 2 + 1]);
    if (lane == 0) {
        float l0 = a0 + blin[0], l1 = a1 + blin[1];
        float mx = fmaxf(l0, l1);
        float e0 = __expf(l0 - mx), e1 = __expf(l1 - mx);
        float inv = 1.f / (e0 + e1);
        out[0] = e0 * inv;
        out[1] = e1 * inv;
    }
}

extern "C" void kernel_launch(void* const* d_in, const int* in_sizes, int n_in,
                              void* d_out, int out_size, void* d_ws, size_t ws_size,
                              hipStream_t stream) {
    const float* x = (const float*)d_in[0];
    const int* ei = (const int*)d_in[1];
    const float* ea = (const float*)d_in[2];
    const int* src = ei;
    const int* dst = ei + NEDGES;
    auto W = [&](int i) { return (const float*)d_in[i]; };

    char* ws = (char*)d_ws;
    size_t off = 0;
    auto alloc = [&](size_t bytes) {
        void* p = ws + off;
        off += (bytes + 255) & ~(size_t)255;
        return p;
    };
    unsigned* XLh = (unsigned*)alloc((size_t)NNODES * 64 * 2);   // packed bf16
    unsigned* XRh = (unsigned*)alloc((size_t)NNODES * 64 * 2);   // packed bf16
    float* Hb = (float*)alloc((size_t)NNODES * 64 * 4);
    int* rowptr = (int*)alloc((size_t)(NNODES + 1) * 4);
    uint2* edata = (uint2*)alloc((size_t)NEDGES * 8);
    float* easum = (float*)alloc(4);
    float* gsum = (float*)alloc(64 * 4);
    int* gcnt = (int*)alloc((size_t)FLATN * 4);
    int* lscan = (int*)alloc((size_t)FLATN * 4);
    int* goff = (int*)alloc((size_t)FLATN * 4);
    int* part2 = (int*)alloc((size_t)SCB * 4);
    int* boff2 = (int*)alloc((size_t)SCB * 4);
    uint2* tmps = (uint2*)Hb;  // 12.8 MB <= Hb's 25.6 MB; Hb dead until layer-1 k_edge

    hipMemsetAsync(easum, 0, 4, stream);
    hipMemsetAsync(gsum, 0, 64 * 4, stream);

    k_lsort<<<NBLK, 256, 0, stream>>>(src, dst, ea, tmps, gcnt, lscan, easum);
    k_part2<<<SCB, 256, 0, stream>>>(gcnt, FLATN, part2);
    k_scanb2<<<1, 1024, 0, stream>>>(part2, SCB, boff2, rowptr);
    k_scanfin2<<<SCB, 256, 0, stream>>>(gcnt, FLATN, boff2, goff);
    k_fsort<<<NB, 256, 0, stream>>>(tmps, lscan, goff, rowptr, edata);

    int gemm_grid = (NNODES + 127) / 128;
    int edge_grid = (NNODES + 3) / 4;

    k_gemm<128><<<gemm_grid, 256, 0, stream>>>(x, W(3), W(4), W(5), W(6), XLh, XRh);
    k_edge<<<edge_grid, 256, 0, stream>>>((const uint2*)XLh, (const uint2*)XRh, rowptr, edata,
                                          W(7), W(8), W(9), easum, Hb);
    k_gemm<64><<<gemm_grid, 256, 0, stream>>>(Hb, W(10), W(11), W(12), W(13), XLh, XRh);
    k_edge<<<edge_grid, 256, 0, stream>>>((const uint2*)XLh, (const uint2*)XRh, rowptr, edata,
                                          W(14), W(15), W(16), easum, Hb);
    k_gemm<64><<<gemm_grid, 256, 0, stream>>>(Hb, W(17), W(18), W(19), W(20), XLh, XRh);
    k_edge<<<edge_grid, 256, 0, stream>>>((const uint2*)XLh, (const uint2*)XRh, rowptr, edata,
                                          W(21), W(22), W(23), easum, Hb);

    k_colsum<<<1024, 256, 0, stream>>>(Hb, gsum);
    k_head<<<1, 64, 0, stream>>>(gsum, W(24), W(25), (float*)d_out);
}

// Round 8
// 441.956 us; speedup vs baseline: 1.5495x; 1.0615x over previous
//
#include <hip/hip_runtime.h>
#include <hip/hip_bf16.h>

#define NNODES 100000
#define NEDGES 1600000
#define NEG_SLOPE 0.2f

#define CHUNK 4096
#define EPT 16                                  // edges per thread in k_lsort
#define NBLK ((NEDGES + CHUNK - 1) / CHUNK)     // 391 sort blocks
#define NB ((NNODES + 255) / 256)               // 391 buckets (256 nodes each)
#define FLATN (NB * NBLK)                       // 152881
#define SCB ((FLATN + 255) / 256)               // 598
#define FCAP 5632                               // bucket entry cap (mean 4092, +24 sigma)

__device__ __forceinline__ float wave_sum64(float v) {
#pragma unroll
    for (int off = 1; off < 64; off <<= 1) v += __shfl_xor(v, off, 64);
    return v;
}

__device__ __forceinline__ int wave_sum64i(int v) {
#pragma unroll
    for (int off = 1; off < 64; off <<= 1) v += __shfl_xor(v, off, 64);
    return v;
}

// pack two f32 -> one uint of 2 bf16 (RNE)
__device__ __forceinline__ unsigned pack_bf2(float a, float b) {
    unsigned ua = __float_as_uint(a), ub = __float_as_uint(b);
    ua = (ua + 0x7FFFu + ((ua >> 16) & 1u)) >> 16;
    ub = (ub + 0x7FFFu + ((ub >> 16) & 1u));
    return ua | (ub & 0xFFFF0000u);
}

__device__ __forceinline__ void unpack_bf8(uint4 w, float* f) {
    f[0] = __uint_as_float(w.x << 16);
    f[1] = __uint_as_float(w.x & 0xFFFF0000u);
    f[2] = __uint_as_float(w.y << 16);
    f[3] = __uint_as_float(w.y & 0xFFFF0000u);
    f[4] = __uint_as_float(w.z << 16);
    f[5] = __uint_as_float(w.z & 0xFFFF0000u);
    f[6] = __uint_as_float(w.w << 16);
    f[7] = __uint_as_float(w.w & 0xFFFF0000u);
}

// ---------------- phase A: per-chunk counting sort by bucket (all-coalesced) ----------------

__global__ __launch_bounds__(256) void k_lsort(const int* __restrict__ src,
                                               const int* __restrict__ dst,
                                               const float* __restrict__ ea,
                                               uint2* __restrict__ tmps,
                                               int* __restrict__ gcnt,
                                               int* __restrict__ lscan,
                                               float* __restrict__ easum) {
    __shared__ uint2 ent[CHUNK];                 // 32 KB
    __shared__ unsigned short perm[CHUNK];       // 8 KB
    __shared__ int hist[NB];
    __shared__ int cur[NB];
    __shared__ float ws[4];
    const int t = threadIdx.x;
    const int j = blockIdx.x;
    const int base = j * CHUNK;
    const int n = min(CHUNK, NEDGES - base);

    for (int b = t; b < NB; b += 256) hist[b] = 0;
    __syncthreads();

    int bkt[EPT];
    float s = 0.f;
#pragma unroll
    for (int k = 0; k < EPT; ++k) {
        const int l = t + k * 256;
        bkt[k] = -1;
        if (l < n) {
            const int i = base + l;
            const int d = dst[i];
            const float e = ea[i];
            const int b = d >> 8;
            bkt[k] = b;
            ent[l] = make_uint2((unsigned)src[i] | ((unsigned)(d & 255) << 17),
                                __float_as_uint(e));
            atomicAdd(&hist[b], 1);
            s += e;
        }
    }
    s = wave_sum64(s);
    if ((t & 63) == 0) ws[t >> 6] = s;
    __syncthreads();
    if (t == 0) atomicAdd(easum, ws[0] + ws[1] + ws[2] + ws[3]);

    // exclusive scan of hist[0..NB) -> cur, wave 0 only (56 lanes x 7 elems)
    if (t < 64) {
        int x[7];
        int run = 0;
#pragma unroll
        for (int q = 0; q < 7; ++q) {
            const int idx = t * 7 + q;
            x[q] = (idx < NB) ? hist[idx] : 0;
            run += x[q];
        }
        int inc = run;
#pragma unroll
        for (int o = 1; o < 64; o <<= 1) {
            int u = __shfl_up(inc, o, 64);
            if (t >= o) inc += u;
        }
        int r = inc - run;   // lane-exclusive
#pragma unroll
        for (int q = 0; q < 7; ++q) {
            const int idx = t * 7 + q;
            if (idx < NB) cur[idx] = r;
            r += x[q];
        }
    }
    __syncthreads();

#pragma unroll
    for (int k = 0; k < EPT; ++k) {
        if (bkt[k] >= 0) {
            const int r = atomicAdd(&cur[bkt[k]], 1);
            perm[r] = (unsigned short)(t + k * 256);
        }
    }
    __syncthreads();

    for (int o = t; o < n; o += 256)
        tmps[base + o] = ent[perm[o]];           // coalesced global write
    for (int b = t; b < NB; b += 256) {
        gcnt[b * NBLK + j] = hist[b];            // bucket-major (for flat scan)
        lscan[j * NB + b] = cur[b] - hist[b];    // local exclusive offset
    }
}

// ---------------- flat exclusive scan of gcnt[FLATN] -> goff ----------------

__global__ __launch_bounds__(256) void k_part2(const int* __restrict__ v, int n,
                                               int* __restrict__ bsum) {
    int i = blockIdx.x * 256 + threadIdx.x;
    int x = (i < n) ? v[i] : 0;
    x = wave_sum64i(x);
    __shared__ int wsh[4];
    if ((threadIdx.x & 63) == 0) wsh[threadIdx.x >> 6] = x;
    __syncthreads();
    if (threadIdx.x == 0) bsum[blockIdx.x] = wsh[0] + wsh[1] + wsh[2] + wsh[3];
}

__global__ __launch_bounds__(1024) void k_scanb2(const int* __restrict__ bsum, int nb,
                                                 int* __restrict__ boff,
                                                 int* __restrict__ rowptr) {
    __shared__ int sh[1024];
    int t = threadIdx.x;
    int v = (t < nb) ? bsum[t] : 0;
    sh[t] = v;
    __syncthreads();
    for (int off = 1; off < 1024; off <<= 1) {
        int u = (t >= off) ? sh[t - off] : 0;
        __syncthreads();
        sh[t] += u;
        __syncthreads();
    }
    if (t < nb) boff[t] = sh[t] - v;
    if (t == 0) rowptr[NNODES] = NEDGES;
}

__global__ __launch_bounds__(256) void k_scanfin2(const int* __restrict__ v, int n,
                                                  const int* __restrict__ boff,
                                                  int* __restrict__ out) {
    int t = threadIdx.x, lane = t & 63, wave = t >> 6;
    int i = blockIdx.x * 256 + t;
    int x = (i < n) ? v[i] : 0;
    int orig = x;
#pragma unroll
    for (int off = 1; off < 64; off <<= 1) {
        int u = __shfl_up(x, off, 64);
        if (lane >= off) x += u;
    }
    __shared__ int wsh[4];
    if (lane == 63) wsh[wave] = x;
    __syncthreads();
    int wexc = 0;
    for (int w = 0; w < wave; ++w) wexc += wsh[w];
    if (i < n) out[i] = boff[blockIdx.x] + wexc + x - orig;
}

// ---------------- phase C: per-bucket gather + LDS counting sort by node ----------------

__global__ __launch_bounds__(256) void k_fsort(const uint2* __restrict__ tmps,
                                               const int* __restrict__ lscan,
                                               const int* __restrict__ goff,
                                               int* __restrict__ rowptr,
                                               uint2* __restrict__ edata) {
    __shared__ uint2 ent[FCAP];                  // 44 KB
    __shared__ unsigned short perm[FCAP];        // 11 KB
    __shared__ int joff[NBLK + 1];
    __shared__ int jsrc[NBLK];
    __shared__ int hist[256];
    __shared__ int cur[256];
    const int b = blockIdx.x;
    const int t = threadIdx.x;
    const int base = goff[b * NBLK];             // bucket base position in edata

    for (int q = t; q < 256; q += 256) hist[q] = 0;
    for (int j = t; j < NBLK; j += 256) {
        joff[j] = goff[b * NBLK + j] - base;
        jsrc[j] = j * CHUNK + lscan[j * NB + b];
    }
    if (t == 0) joff[NBLK] = ((b == NB - 1) ? NEDGES : goff[(b + 1) * NBLK]) - base;
    __syncthreads();
    const int T = min(joff[NBLK], FCAP);

    for (int idx = t; idx < T; idx += 256) {
        int lo = 0, hi = NBLK;
        while (hi - lo > 1) { int mid = (lo + hi) >> 1; if (joff[mid] <= idx) lo = mid; else hi = mid; }
        const uint2 e = tmps[jsrc[lo] + (idx - joff[lo])];   // piecewise-coalesced
        ent[idx] = e;
        atomicAdd(&hist[(e.x >> 17) & 255u], 1);
    }
    __syncthreads();

    // exclusive scan hist[0..256) -> cur, wave 0 (64 lanes x 4)
    if (t < 64) {
        int x[4];
        int run = 0;
#pragma unroll
        for (int q = 0; q < 4; ++q) { x[q] = hist[t * 4 + q]; run += x[q]; }
        int inc = run;
#pragma unroll
        for (int o = 1; o < 64; o <<= 1) {
            int u = __shfl_up(inc, o, 64);
            if (t >= o) inc += u;
        }
        int r = inc - run;
#pragma unroll
        for (int q = 0; q < 4; ++q) { cur[t * 4 + q] = r; r += x[q]; }
    }
    __syncthreads();

    {
        const int i = b * 256 + t;
        if (i < NNODES) rowptr[i] = base + cur[t];
    }
    __syncthreads();    // rowptr reads of cur must complete before rank mutation

    for (int idx = t; idx < T; idx += 256) {
        const int d = (int)((ent[idx].x >> 17) & 255u);
        const int r = atomicAdd(&cur[d], 1);
        perm[r] = (unsigned short)idx;
    }
    __syncthreads();
    for (int k = t; k < T; k += 256)
        edata[base + k] = ent[perm[k]];          // coalesced global write
}

// ---------------- register-tiled dual GEMM: [XL|XR] = X @ [Wl|Wr] + [bl|br] ----------------
// Outputs packed bf16 (2 per uint): row stride 32 uints.

template <int K>
__global__ __launch_bounds__(256) void k_gemm(const float* __restrict__ X,
                                              const float* __restrict__ Wl,
                                              const float* __restrict__ bl,
                                              const float* __restrict__ Wr,
                                              const float* __restrict__ br,
                                              unsigned* __restrict__ XLh,
                                              unsigned* __restrict__ XRh) {
    constexpr int KC = 32;
    __shared__ float sX[KC][132];
    __shared__ float sW[KC][128];
    const int t = threadIdx.x;
    const int tc = t & 15, tr = t >> 4;
    const int r0 = blockIdx.x * 128;

    float acc[8][8] = {};

    for (int kc = 0; kc < K; kc += KC) {
#pragma unroll
        for (int i = 0; i < 4; ++i) {
            int l = t + 256 * i;
            int row = l >> 3;
            int kq = (l & 7) * 4;
            int rr = min(r0 + row, NNODES - 1);
            const float4 v = *(const float4*)&X[(size_t)rr * K + kc + kq];
            sX[kq + 0][row] = v.x;
            sX[kq + 1][row] = v.y;
            sX[kq + 2][row] = v.z;
            sX[kq + 3][row] = v.w;
        }
#pragma unroll
        for (int i = 0; i < 4; ++i) {
            int l = t + 256 * i;
            int k = l >> 5;
            int cq = l & 31;
            const float* sp = (cq < 16) ? &Wl[(size_t)(kc + k) * 64 + cq * 4]
                                        : &Wr[(size_t)(kc + k) * 64 + (cq - 16) * 4];
            *(float4*)&sW[k][cq * 4] = *(const float4*)sp;
        }
        __syncthreads();
#pragma unroll 4
        for (int k = 0; k < KC; ++k) {
            float xf[8], wf[8];
            *(float4*)&xf[0] = *(const float4*)&sX[k][tr * 8];
            *(float4*)&xf[4] = *(const float4*)&sX[k][tr * 8 + 4];
            *(float4*)&wf[0] = *(const float4*)&sW[k][tc * 8];
            *(float4*)&wf[4] = *(const float4*)&sW[k][tc * 8 + 4];
#pragma unroll
            for (int i2 = 0; i2 < 8; ++i2)
#pragma unroll
                for (int j = 0; j < 8; ++j)
                    acc[i2][j] += xf[i2] * wf[j];
        }
        __syncthreads();
    }

    const bool isL = (tc < 8);
    const int cb = isL ? tc * 8 : tc * 8 - 64;
    const float* bb = isL ? bl : br;
    unsigned* OUT = isL ? XLh : XRh;
    float4 b0 = *(const float4*)&bb[cb];
    float4 b1 = *(const float4*)&bb[cb + 4];
#pragma unroll
    for (int i = 0; i < 8; ++i) {
        int row = r0 + tr * 8 + i;
        if (row < NNODES) {
            uint4 v;
            v.x = pack_bf2(acc[i][0] + b0.x, acc[i][1] + b0.y);
            v.y = pack_bf2(acc[i][2] + b0.z, acc[i][3] + b0.w);
            v.z = pack_bf2(acc[i][4] + b1.x, acc[i][5] + b1.y);
            v.w = pack_bf2(acc[i][6] + b1.z, acc[i][7] + b1.w);
            *(uint4*)&OUT[(size_t)row * 32 + (cb >> 1)] = v;
        }
    }
}

// ---------------- fused GATv2 edge pass ----------------
// One wave per node (grid exactly NNODES/4 blocks x 4 waves, one node each).
// lane = 8*group + fl; group g handles edge e+g (8 edges/iter); lane holds
// features [fl*8, fl*8+8) unpacked from one uint4 (16 B) of packed bf16.
// Online softmax: per-group partial S (exact deferred reduction), ballot-gated
// rescale, LDS-transpose final combine.

__global__ __launch_bounds__(256) void k_edge(const uint4* __restrict__ XLh,
                                              const uint4* __restrict__ XRh,
                                              const int* __restrict__ rowptr,
                                              const uint2* __restrict__ edata,
                                              const float* __restrict__ We,
                                              const float* __restrict__ att,
                                              const float* __restrict__ bias,
                                              const float* __restrict__ easum,
                                              float* __restrict__ H) {
    __shared__ float red[4][8][64];              // 8 KB: [wave][group][feature]
    const int wave = threadIdx.x >> 6, lane = threadIdx.x & 63;
    const int g = lane >> 3, fl = lane & 7;
    const int fo = fl * 8;
    float We8[8], att8[8];
    *(float4*)&We8[0] = *(const float4*)&We[fo];
    *(float4*)&We8[4] = *(const float4*)&We[fo + 4];
    *(float4*)&att8[0] = *(const float4*)&att[fo];
    *(float4*)&att8[4] = *(const float4*)&att[fo + 4];
    const float bias_l = bias[lane];
    const float ea_mean = easum[0] * (1.0f / NEDGES);

    const int i = blockIdx.x * 4 + wave;         // always < NNODES (exact grid)

    float xr8[8], xl8[8], v8[8], acc8[8];
    unpack_bf8(XRh[(size_t)i * 8 + fl], xr8);
    unpack_bf8(XLh[(size_t)i * 8 + fl], xl8);

    // self-loop (src=i, ea=ea_mean): identical in all groups -> wave-uniform M
    float pt = 0.f;
#pragma unroll
    for (int f = 0; f < 8; ++f) {
        float m = xl8[f] + xr8[f] + ea_mean * We8[f];
        m = fmaxf(m, 0.f) + NEG_SLOPE * fminf(m, 0.f);
        pt = fmaf(m, att8[f], pt);
    }
    pt += __shfl_xor(pt, 1);
    pt += __shfl_xor(pt, 2);
    pt += __shfl_xor(pt, 4);
    float M = pt;
    float S = (g == 0) ? 1.f : 0.f;              // per-group partial denominator
#pragma unroll
    for (int f = 0; f < 8; ++f) acc8[f] = (g == 0) ? xl8[f] : 0.f;

    const int e0 = rowptr[i], e1 = rowptr[i + 1];
    uint2 se = make_uint2(0u, 0u);
    if (e0 + g < e1) se = edata[e0 + g];
    for (int e = e0; e < e1; e += 8) {
        const uint2 se_cur = se;
        const bool valid = (e + g) < e1;
        if (e + 8 + g < e1) se = edata[e + 8 + g];   // prefetch next batch
        const int s = (int)(se_cur.x & 0x1FFFFu);
        const float eav = __uint_as_float(se_cur.y);
        unpack_bf8(XLh[(size_t)s * 8 + fl], v8);

        float d = 0.f;
#pragma unroll
        for (int f = 0; f < 8; ++f) {
            float b = v8[f] + xr8[f] + eav * We8[f];
            b = fmaxf(b, 0.f) + NEG_SLOPE * fminf(b, 0.f);
            d = fmaf(b, att8[f], d);
        }
        d += __shfl_xor(d, 1);
        d += __shfl_xor(d, 2);
        d += __shfl_xor(d, 4);                   // group-uniform logit
        const float a = valid ? d : -1e30f;

        if (__any(a > M)) {                      // ballot (no LDS); wave-uniform
            float am = fmaxf(a, __shfl_xor(a, 8));
            am = fmaxf(am, __shfl_xor(am, 16));
            am = fmaxf(am, __shfl_xor(am, 32));
            const float sc = __expf(M - am);     // exact rescale
            S *= sc;
#pragma unroll
            for (int f = 0; f < 8; ++f) acc8[f] *= sc;
            M = am;
        }
        const float p = __expf(a - M);           // 0 for invalid groups
        S += p;                                  // group-partial (deferred reduce)
#pragma unroll
        for (int f = 0; f < 8; ++f) acc8[f] = fmaf(p, v8[f], acc8[f]);
    }

    // reduce S across groups (xor 8/16/32 touches g bits only)
    S += __shfl_xor(S, 8);
    S += __shfl_xor(S, 16);
    S += __shfl_xor(S, 32);

    // transpose-combine acc8 across groups via LDS
    *(float4*)&red[wave][g][fo] = *(float4*)&acc8[0];
    *(float4*)&red[wave][g][fo + 4] = *(float4*)&acc8[4];
    __syncthreads();                             // uniform: every thread has one node
    float o = 0.f;
#pragma unroll
    for (int gg = 0; gg < 8; ++gg) o += red[wave][gg][lane];
    o = fmaxf(o / S + bias_l, 0.f);              // bias + fused ReLU
    H[(size_t)i * 64 + lane] = o;                // 64-lane coalesced store
}

// ---------------- tail: mean pool + linear + softmax ----------------

__global__ __launch_bounds__(256) void k_colsum(const float* __restrict__ H,
                                                float* __restrict__ gsum) {
    int wave = threadIdx.x >> 6, lane = threadIdx.x & 63;
    float s = 0.f;
    for (int r = blockIdx.x * 4 + wave; r < NNODES; r += gridDim.x * 4)
        s += H[(size_t)r * 64 + lane];
    __shared__ float ls[4][64];
    ls[wave][lane] = s;
    __syncthreads();
    if (wave == 0) {
        s = ls[0][lane] + ls[1][lane] + ls[2][lane] + ls[3][lane];
        atomicAdd(&gsum[lane], s);
    }
}

__global__ __launch_bounds__(64) void k_head(const float* __restrict__ gsum,
                                             const float* __restrict__ Wlin,
                                             const float* __restrict__ blin,
                                             float* __restrict__ out) {
    int lane = threadIdx.x;
    float g = gsum[lane] * (1.0f / NNODES);
    float a0 = wave_sum64(g * Wlin[lane * 2 + 0]);
    float a1 = wave_sum64(g * Wlin[lane * 2 + 1]);
    if (lane == 0) {
        float l0 = a0 + blin[0], l1 = a1 + blin[1];
        float mx = fmaxf(l0, l1);
        float e0 = __expf(l0 - mx), e1 = __expf(l1 - mx);
        float inv = 1.f / (e0 + e1);
        out[0] = e0 * inv;
        out[1] = e1 * inv;
    }
}

extern "C" void kernel_launch(void* const* d_in, const int* in_sizes, int n_in,
                              void* d_out, int out_size, void* d_ws, size_t ws_size,
                              hipStream_t stream) {
    const float* x = (const float*)d_in[0];
    const int* ei = (const int*)d_in[1];
    const float* ea = (const float*)d_in[2];
    const int* src = ei;
    const int* dst = ei + NEDGES;
    auto W = [&](int i) { return (const float*)d_in[i]; };

    char* ws = (char*)d_ws;
    size_t off = 0;
    auto alloc = [&](size_t bytes) {
        void* p = ws + off;
        off += (bytes + 255) & ~(size_t)255;
        return p;
    };
    unsigned* XLh = (unsigned*)alloc((size_t)NNODES * 64 * 2);   // packed bf16
    unsigned* XRh = (unsigned*)alloc((size_t)NNODES * 64 * 2);   // packed bf16
    float* Hb = (float*)alloc((size_t)NNODES * 64 * 4);
    int* rowptr = (int*)alloc((size_t)(NNODES + 1) * 4);
    uint2* edata = (uint2*)alloc((size_t)NEDGES * 8);
    float* easum = (float*)alloc(4);
    float* gsum = (float*)alloc(64 * 4);
    int* gcnt = (int*)alloc((size_t)FLATN * 4);
    int* lscan = (int*)alloc((size_t)FLATN * 4);
    int* goff = (int*)alloc((size_t)FLATN * 4);
    int* part2 = (int*)alloc((size_t)SCB * 4);
    int* boff2 = (int*)alloc((size_t)SCB * 4);
    uint2* tmps = (uint2*)Hb;  // 12.8 MB <= Hb's 25.6 MB; Hb dead until layer-1 k_edge

    hipMemsetAsync(easum, 0, 4, stream);
    hipMemsetAsync(gsum, 0, 64 * 4, stream);

    k_lsort<<<NBLK, 256, 0, stream>>>(src, dst, ea, tmps, gcnt, lscan, easum);
    k_part2<<<SCB, 256, 0, stream>>>(gcnt, FLATN, part2);
    k_scanb2<<<1, 1024, 0, stream>>>(part2, SCB, boff2, rowptr);
    k_scanfin2<<<SCB, 256, 0, stream>>>(gcnt, FLATN, boff2, goff);
    k_fsort<<<NB, 256, 0, stream>>>(tmps, lscan, goff, rowptr, edata);

    int gemm_grid = (NNODES + 127) / 128;
    int edge_grid = NNODES / 4;   // exact: one wave per node, no stride loop

    k_gemm<128><<<gemm_grid, 256, 0, stream>>>(x, W(3), W(4), W(5), W(6), XLh, XRh);
    k_edge<<<edge_grid, 256, 0, stream>>>((const uint4*)XLh, (const uint4*)XRh, rowptr, edata,
                                          W(7), W(8), W(9), easum, Hb);
    k_gemm<64><<<gemm_grid, 256, 0, stream>>>(Hb, W(10), W(11), W(12), W(13), XLh, XRh);
    k_edge<<<edge_grid, 256, 0, stream>>>((const uint4*)XLh, (const uint4*)XRh, rowptr, edata,
                                          W(14), W(15), W(16), easum, Hb);
    k_gemm<64><<<gemm_grid, 256, 0, stream>>>(Hb, W(17), W(18), W(19), W(20), XLh, XRh);
    k_edge<<<edge_grid, 256, 0, stream>>>((const uint4*)XLh, (const uint4*)XRh, rowptr, edata,
                                          W(21), W(22), W(23), easum, Hb);

    k_colsum<<<1024, 256, 0, stream>>>(Hb, gsum);
    k_head<<<1, 64, 0, stream>>>(gsum, W(24), W(25), (float*)d_out);
}